// Round 1
// baseline (471.018 us; speedup 1.0000x reference)
//
#include <hip/hip_runtime.h>
#include <math.h>

#define N_NODES 100000
#define N_EDGES 800000
#define D_IN    64
#define HC      128   // H*C
#define CAP     48    // max in-degree slots (Poisson(8): P(>48) ~ 0)
#define GN      128   // gemm nodes per block

// tanh-approx gelu (jax.nn.gelu default approximate=True)
__device__ __forceinline__ float gelu_f(float x) {
    float x3 = x * x * x;
    float y  = 0.7978845608028654f * (x + 0.044715f * x3);
    float t = 1.0f - 2.0f / (__expf(2.0f * y) + 1.0f);
    return 0.5f * x * (1.0f + t);
}

// sum across a 16-lane row via DPP row_ror (pure VALU, no ds_swizzle)
__device__ __forceinline__ float red16(float x) {
    x += __int_as_float(__builtin_amdgcn_mov_dpp(__float_as_int(x), 0x128, 0xF, 0xF, true)); // ror:8
    x += __int_as_float(__builtin_amdgcn_mov_dpp(__float_as_int(x), 0x124, 0xF, 0xF, true)); // ror:4
    x += __int_as_float(__builtin_amdgcn_mov_dpp(__float_as_int(x), 0x122, 0xF, 0xF, true)); // ror:2
    x += __int_as_float(__builtin_amdgcn_mov_dpp(__float_as_int(x), 0x121, 0xF, 0xF, true)); // ror:1
    return x;
}

// ---------------- CSR-by-capacity scatter (once; shared by both layers) ----
__global__ void scatter_kernel(const int* __restrict__ edges,
                               int* __restrict__ cnt, int* __restrict__ tbl) {
    int e = blockIdx.x * blockDim.x + threadIdx.x;
    if (e >= N_EDGES) return;
    int s = edges[e];            // src row
    int d = edges[N_EDGES + e];  // dst row
    int slot = atomicAdd(&cnt[d], 1);
    if (slot < CAP) tbl[d * CAP + slot] = s;
}

// ---------------- xl/xr GEMM: [N,64] @ [64,128] + b -------------------------
// Block = 128 nodes staged through LDS (coalesced global loads; pad stride 68
// floats -> conflict-free b128 row reads). Waves 0-1 compute XL (128 ch of
// their node), waves 2-3 compute XR; sel is readfirstlane'd so W/b addresses
// stay uniform -> s_load. X is read once per matrix (was 4x total).
__global__ __launch_bounds__(256) void gemm_kernel(
    const float* __restrict__ X,
    const float* __restrict__ Wl, const float* __restrict__ bl,
    const float* __restrict__ Wr, const float* __restrict__ br,
    float* __restrict__ XL, float* __restrict__ XR) {
    __shared__ float xs[GN * 68];
    const int t  = threadIdx.x;
    const int n0 = blockIdx.x * GN;

    // stage X tile: 128 rows x 16 float4 = 2048 float4, 8 per thread, coalesced
    #pragma unroll
    for (int p = 0; p < 8; ++p) {
        int f   = p * 256 + t;
        int row = f >> 4, q = f & 15;
        int n   = n0 + row;
        float4 val = make_float4(0.0f, 0.0f, 0.0f, 0.0f);
        if (n < N_NODES) val = *(const float4*)(X + (size_t)n * D_IN + 4 * q);
        *(float4*)(&xs[row * 68 + 4 * q]) = val;
    }
    __syncthreads();

    const int node = t & (GN - 1);
    const int sel  = __builtin_amdgcn_readfirstlane(t >> 7);  // wave-uniform
    const float* __restrict__ W   = sel ? Wr : Wl;
    const float* __restrict__ b   = sel ? br : bl;
    float*       __restrict__ OUT = sel ? XR : XL;

    float x[64];
    #pragma unroll
    for (int q = 0; q < 16; ++q) {
        float4 val = *(const float4*)(&xs[node * 68 + 4 * q]);
        x[4*q] = val.x; x[4*q+1] = val.y; x[4*q+2] = val.z; x[4*q+3] = val.w;
    }

    const int n = n0 + node;
    if (n >= N_NODES) return;

    #pragma unroll 1
    for (int c0 = 0; c0 < HC; c0 += 16) {
        float acc[16];
        #pragma unroll
        for (int i = 0; i < 16; ++i) acc[i] = b[c0 + i];        // s_load
        #pragma unroll
        for (int k = 0; k < 64; ++k) {                          // x const-idx
            #pragma unroll
            for (int i = 0; i < 16; ++i)
                acc[i] = fmaf(x[k], W[k * HC + c0 + i], acc[i]); // uniform W
        }
        float* o = &OUT[(size_t)n * HC + c0];                   // 64B line
        #pragma unroll
        for (int q = 0; q < 4; ++q)
            *(float4*)(o + 4 * q) = make_float4(acc[4*q], acc[4*q+1],
                                                acc[4*q+2], acc[4*q+3]);
    }
}

// ---------------- wave-per-node aggregation: 2 edges/iter, 4 ch/lane --------
// lanes 0-31: edge i, lanes 32-63: edge i+1. Within a 32-lane half:
// lanes 0-15 head0, 16-31 head1; lane li handles channels 4*li..4*li+3.
// Score reduce = 4 DPP row_ror adds (no DS ops). Softmax uses a FIXED shift
// m0 = e_self (same alpha ratios as running-max; e - e_self is O(+-15) here,
// safe in fp32) -> accumulation is associative: 1 exp + 4 fma per half.
__global__ __launch_bounds__(256) void aggregate_kernel(
    const float* __restrict__ XL, const float* __restrict__ XR,
    const int* __restrict__ cnt, const int* __restrict__ tbl,
    const float* __restrict__ att, const float* __restrict__ bias,
    float* __restrict__ Y, int applyGelu) {
    const int v = (blockIdx.x * blockDim.x + threadIdx.x) >> 6;
    const int lane = threadIdx.x & 63;
    if (v >= N_NODES) return;
    const int half = lane >> 5;          // which edge of the pair
    const int li   = lane & 15;
    const int hc   = ((lane >> 4) & 1) * 64 + 4 * li;

    const float4 a4  = *(const float4*)(att + hc);
    const float4 xr4 = *(const float4*)(XR + (size_t)v * HC + hc);
    const float4 xl4 = *(const float4*)(XL + (size_t)v * HC + hc);

    // self edge: z = xl[v] + xr[v]; its score is the shift m0
    float z0 = xl4.x + xr4.x, z1 = xl4.y + xr4.y;
    float z2 = xl4.z + xr4.z, z3 = xl4.w + xr4.w;
    float p = fmaxf(z0, 0.2f*z0) * a4.x + fmaxf(z1, 0.2f*z1) * a4.y
            + fmaxf(z2, 0.2f*z2) * a4.z + fmaxf(z3, 0.2f*z3) * a4.w;
    const float m0 = red16(p);

    // self contributes exp(0)=1 exactly once (half 0 only)
    float s  = half ? 0.0f : 1.0f;
    float ax = half ? 0.0f : xl4.x;
    float ay = half ? 0.0f : xl4.y;
    float az = half ? 0.0f : xl4.z;
    float aw = half ? 0.0f : xl4.w;

    int deg = cnt[v];
    if (deg > CAP) deg = CAP;
    int u_l = (lane < deg) ? tbl[v * CAP + lane] : 0;

    const float* __restrict__ XLh = XL + hc;

    // depth-3 pair prefetch (6 edges in flight)
    float4 x0 = make_float4(0,0,0,0), x1 = x0, x2 = x0;
    if (deg > 0) { int u = __shfl(u_l, 0 + half); x0 = *(const float4*)(XLh + (size_t)u * HC); }
    if (deg > 2) { int u = __shfl(u_l, 2 + half); x1 = *(const float4*)(XLh + (size_t)u * HC); }
    if (deg > 4) { int u = __shfl(u_l, 4 + half); x2 = *(const float4*)(XLh + (size_t)u * HC); }

    for (int i = 0; i < deg; i += 2) {
        float4 xc = x0; x0 = x1; x1 = x2;
        if (i + 6 < deg) {
            int u = __shfl(u_l, i + 6 + half);
            x2 = *(const float4*)(XLh + (size_t)u * HC);
        }
        z0 = xc.x + xr4.x; z1 = xc.y + xr4.y;
        z2 = xc.z + xr4.z; z3 = xc.w + xr4.w;
        p = fmaxf(z0, 0.2f*z0) * a4.x + fmaxf(z1, 0.2f*z1) * a4.y
          + fmaxf(z2, 0.2f*z2) * a4.z + fmaxf(z3, 0.2f*z3) * a4.w;
        p = red16(p);
        if (half && (i + 1 >= deg)) p = -1e30f;   // odd-deg tail -> weight 0
        float w = __expf(p - m0);
        s += w;
        ax = fmaf(w, xc.x, ax); ay = fmaf(w, xc.y, ay);
        az = fmaf(w, xc.z, az); aw = fmaf(w, xc.w, aw);
    }

    // merge the two edge streams (same head/channels at lane^32)
    s  += __shfl_xor(s, 32);
    ax += __shfl_xor(ax, 32); ay += __shfl_xor(ay, 32);
    az += __shfl_xor(az, 32); aw += __shfl_xor(aw, 32);

    float inv = 1.0f / (s + 1e-16f);
    ax *= inv; ay *= inv; az *= inv; aw *= inv;

    // mean over heads (head1 sits at lane^16)
    ax += __shfl_xor(ax, 16); ay += __shfl_xor(ay, 16);
    az += __shfl_xor(az, 16); aw += __shfl_xor(aw, 16);
    ax *= 0.5f; ay *= 0.5f; az *= 0.5f; aw *= 0.5f;

    if (lane < 16) {
        const float4 b4 = *(const float4*)(bias + 4 * li);
        ax += b4.x; ay += b4.y; az += b4.z; aw += b4.w;
        if (applyGelu) { ax = gelu_f(ax); ay = gelu_f(ay); az = gelu_f(az); aw = gelu_f(aw); }
        *(float4*)(Y + (size_t)v * 64 + 4 * li) = make_float4(ax, ay, az, aw);
    }
}

extern "C" void kernel_launch(void* const* d_in, const int* in_sizes, int n_in,
                              void* d_out, int out_size, void* d_ws, size_t ws_size,
                              hipStream_t stream) {
    const float* X     = (const float*)d_in[0];
    const int*   edges = (const int*)d_in[1];
    const float* Wl    = (const float*)d_in[2];
    const float* bl    = (const float*)d_in[3];
    const float* Wr    = (const float*)d_in[4];
    const float* br    = (const float*)d_in[5];
    const float* att   = (const float*)d_in[6];
    const float* bias  = (const float*)d_in[7];

    char* ws = (char*)d_ws;
    float* XLb = (float*)ws;                                          // N*128 f32
    float* XRb = (float*)(ws + (size_t)N_NODES * HC * 4);             // N*128 f32
    float* Yb  = (float*)(ws + (size_t)N_NODES * HC * 8);             // N*64 f32
    int*   cnt = (int*)(ws + (size_t)N_NODES * HC * 8 + (size_t)N_NODES * 64 * 4);
    int*   tbl = cnt + N_NODES;                                       // N*CAP ints

    hipMemsetAsync(cnt, 0, N_NODES * sizeof(int), stream);
    scatter_kernel<<<(N_EDGES + 255) / 256, 256, 0, stream>>>(edges, cnt, tbl);

    const int gemm_grid = (N_NODES + GN - 1) / GN;
    const int agg_grid  = (N_NODES * 64 + 255) / 256;

    // layer 0
    gemm_kernel<<<gemm_grid, 256, 0, stream>>>(X, Wl, bl, Wr, br, XLb, XRb);
    aggregate_kernel<<<agg_grid, 256, 0, stream>>>(XLb, XRb, cnt, tbl, att, bias, Yb, 1);
    // layer 1
    gemm_kernel<<<gemm_grid, 256, 0, stream>>>(Yb, Wl + 8192, bl + 128, Wr + 8192, br + 128, XLb, XRb);
    aggregate_kernel<<<agg_grid, 256, 0, stream>>>(XLb, XRb, cnt, tbl, att + 128, bias + 64,
                                                   (float*)d_out, 0);
}